// Round 3
// baseline (1999.687 us; speedup 1.0000x reference)
//
#include <hip/hip_runtime.h>
#include <hip/hip_bf16.h>

typedef unsigned short u16;
typedef unsigned int   u32;

#define N_NODES 50000
#define N_EDGES 800000
#define F_IN    256

// bf16 helpers (RNE rounding)
__device__ __forceinline__ float bf2f(u16 u) {
  u32 x = ((u32)u) << 16;
  return __uint_as_float(x);
}
__device__ __forceinline__ u16 f2bf(float f) {
  u32 x = __float_as_uint(f);
  u32 r = (x + 0x7fffu + ((x >> 16) & 1u)) >> 16;
  return (u16)r;
}

// DT: 0 = bf16 device buffers, 1 = f32 device buffers
template<int DT> __device__ __forceinline__ float ldf(const void* p, size_t i) {
  if (DT == 0) return bf2f(((const u16*)p)[i]);
  return ((const float*)p)[i];
}
template<int DT> __device__ __forceinline__ void ld4(const void* p, size_t i, float v[4]) {
  if (DT == 0) {
    const uint2 r = *reinterpret_cast<const uint2*>((const u16*)p + i);
    v[0] = bf2f((u16)(r.x & 0xffffu)); v[1] = bf2f((u16)(r.x >> 16));
    v[2] = bf2f((u16)(r.y & 0xffffu)); v[3] = bf2f((u16)(r.y >> 16));
  } else {
    const float4 r = *reinterpret_cast<const float4*>((const float*)p + i);
    v[0] = r.x; v[1] = r.y; v[2] = r.z; v[3] = r.w;
  }
}

// ---------------- dtype detector: decode leading words as bf16 --------------
// f32 data: low half-words (even u16 indices) are random mantissa bits ->
// ~46% have implausible exponents. bf16 N(0,1) data: 0%.
__global__ __launch_bounds__(64)
void detect_dtype(const u16* __restrict__ feats, int* __restrict__ flag)
{
  const int lane = threadIdx.x;
  const u16 u = feats[lane * 2];
  const int ex = (u >> 7) & 0xFF;
  const unsigned long long m = __ballot(ex >= 137);  // |v| >= 1024 or NaN/Inf
  if (lane == 0) *flag = (__popcll(m) > 8) ? 1 : 0;
}

// ---------------- C = A * B^T (+bias), f32 acc, C always bf16 ---------------
// MODE 1: A row = concat(features, emb[labels[row]]), K=512.
#define TBM 64
#define TBN 64
#define TBK 16

template<int MODE, int ADT, int BDT>
__global__ __launch_bounds__(256)
void gemm_bt(const int* __restrict__ flag, int want,
             const void* __restrict__ A, const void* __restrict__ B,
             const void* __restrict__ bias, u16* __restrict__ C,
             const void* __restrict__ feats, const void* __restrict__ emb,
             const int* __restrict__ labels, int M, int Nc, int K)
{
  if (*flag != want) return;
  __shared__ float As[TBK][TBM + 4];
  __shared__ float Bs[TBK][TBN + 4];
  const int tid = threadIdx.x;
  const int tx = tid & 15, ty = tid >> 4;
  const int bm = blockIdx.x * TBM, bn = blockIdx.y * TBN;
  const int lrow = tid >> 2, lkq = (tid & 3) << 2;
  float acc[4][4] = {};
  for (int k0 = 0; k0 < K; k0 += TBK) {
    float va[4] = {0.f, 0.f, 0.f, 0.f};
    {
      const int gr = bm + lrow;
      if (gr < M) {
        const int k = k0 + lkq;
        if (MODE == 1) {
          if (k < F_IN) ld4<ADT>(feats, (size_t)gr * F_IN + k, va);
          else          ld4<ADT>(emb, (size_t)labels[gr] * F_IN + (k - F_IN), va);
        } else {
          ld4<ADT>(A, (size_t)gr * K + k, va);
        }
      }
    }
    float vb[4] = {0.f, 0.f, 0.f, 0.f};
    {
      const int gc = bn + lrow;
      if (gc < Nc) ld4<BDT>(B, (size_t)gc * K + k0 + lkq, vb);
    }
#pragma unroll
    for (int i = 0; i < 4; ++i) As[lkq + i][lrow] = va[i];
#pragma unroll
    for (int i = 0; i < 4; ++i) Bs[lkq + i][lrow] = vb[i];
    __syncthreads();
#pragma unroll
    for (int k = 0; k < TBK; ++k) {
      float a[4], b[4];
#pragma unroll
      for (int i = 0; i < 4; ++i) a[i] = As[k][(ty << 2) + i];
#pragma unroll
      for (int j = 0; j < 4; ++j) b[j] = Bs[k][(tx << 2) + j];
#pragma unroll
      for (int i = 0; i < 4; ++i)
#pragma unroll
        for (int j = 0; j < 4; ++j)
          acc[i][j] = fmaf(a[i], b[j], acc[i][j]);
    }
    __syncthreads();
  }
#pragma unroll
  for (int i = 0; i < 4; ++i) {
    const int gr = bm + (ty << 2) + i;
    if (gr >= M) continue;
#pragma unroll
    for (int j = 0; j < 4; ++j) {
      const int gc = bn + (tx << 2) + j;
      if (gc >= Nc) continue;
      float v = acc[i][j];
      if (bias) v += ldf<BDT>(bias, gc);
      C[(size_t)gr * Nc + gc] = f2bf(v);
    }
  }
}

// ---------------- LayerNorm(1024) + ReLU, in place (y is bf16) --------------
template<int DT>
__global__ __launch_bounds__(256)
void ln_relu(const int* __restrict__ flag, int want, u16* __restrict__ y,
             const void* __restrict__ g, const void* __restrict__ b)
{
  if (*flag != want) return;
  const int row = blockIdx.x;
  u16* p = y + (size_t)row * 1024;
  const int t = threadIdx.x;
  const uint2 r = *reinterpret_cast<const uint2*>(p + (t << 2));
  float v[4] = { bf2f((u16)(r.x & 0xffffu)), bf2f((u16)(r.x >> 16)),
                 bf2f((u16)(r.y & 0xffffu)), bf2f((u16)(r.y >> 16)) };
  float s = v[0] + v[1] + v[2] + v[3];
  float q = v[0]*v[0] + v[1]*v[1] + v[2]*v[2] + v[3]*v[3];
#pragma unroll
  for (int off = 1; off < 64; off <<= 1) { s += __shfl_xor(s, off); q += __shfl_xor(q, off); }
  __shared__ float ss[4], sq[4];
  const int w = t >> 6, lane = t & 63;
  if (lane == 0) { ss[w] = s; sq[w] = q; }
  __syncthreads();
  const float tot  = ss[0] + ss[1] + ss[2] + ss[3];
  const float totq = sq[0] + sq[1] + sq[2] + sq[3];
  const float mu = tot * (1.f / 1024.f);
  const float var = totq * (1.f / 1024.f) - mu * mu;
  const float is = rsqrtf(var + 1e-5f);
  u16 o[4];
#pragma unroll
  for (int i = 0; i < 4; ++i) {
    const int c = (t << 2) + i;
    float val = (v[i] - mu) * is * ldf<DT>(g, c) + ldf<DT>(b, c);
    o[i] = f2bf(fmaxf(val, 0.f));
  }
  uint2 wv;
  wv.x = (u32)o[0] | ((u32)o[1] << 16);
  wv.y = (u32)o[2] | ((u32)o[3] << 16);
  *reinterpret_cast<uint2*>(p + (t << 2)) = wv;
}

// ---------------- el/er: one thread per (node, head); feat is bf16 ----------
template<int DT>
__global__ __launch_bounds__(256)
void gat_elr(const int* __restrict__ flag, int want,
             const u16* __restrict__ feat, const void* __restrict__ al,
             const void* __restrict__ ar, float* __restrict__ el, float* __restrict__ er)
{
  if (*flag != want) return;
  const int idx = blockIdx.x * 256 + threadIdx.x;
  if (idx >= N_NODES * 4) return;
  const int n = idx >> 2, h = idx & 3;
  const u16* f = feat + (size_t)n * 256 + h * 64;
  float sl = 0.f, sr = 0.f;
#pragma unroll 8
  for (int d = 0; d < 64; ++d) {
    const float fv = bf2f(f[d]);
    sl = fmaf(fv, ldf<DT>(al, h * 64 + d), sl);
    sr = fmaf(fv, ldf<DT>(ar, h * 64 + d), sr);
  }
  el[idx] = sl; er[idx] = sr;
}

// ---------------- edge scores: leaky_relu(el[src]+er[dst]) ------------------
__global__ __launch_bounds__(256)
void edge_scores(const float* __restrict__ el, const float* __restrict__ er,
                 const int* __restrict__ src, const int* __restrict__ dst,
                 float* __restrict__ s)
{
  const int e = blockIdx.x * 256 + threadIdx.x;
  if (e >= N_EDGES) return;
  const float4 l = *reinterpret_cast<const float4*>(el + (size_t)src[e] * 4);
  const float4 r = *reinterpret_cast<const float4*>(er + (size_t)dst[e] * 4);
  float4 o; float x;
  x = l.x + r.x; o.x = x > 0.f ? x : 0.2f * x;
  x = l.y + r.y; o.y = x > 0.f ? x : 0.2f * x;
  x = l.z + r.z; o.z = x > 0.f ? x : 0.2f * x;
  x = l.w + r.w; o.w = x > 0.f ? x : 0.2f * x;
  *reinterpret_cast<float4*>(s + (size_t)e * 4) = o;
}

// ---------------- CSR build --------------------------------------------------
__global__ __launch_bounds__(256)
void count_edges(const int* __restrict__ dst, int* __restrict__ cnt)
{
  const int e = blockIdx.x * 256 + threadIdx.x;
  if (e < N_EDGES) atomicAdd(&cnt[dst[e]], 1);
}

// single-wave int4 scan: no shared memory, no cross-wave handoff
__global__ __launch_bounds__(64)
void scan_rowptr(const int* __restrict__ cnt, int* __restrict__ rowptr)
{
  const int lane = threadIdx.x;
  int carry = 0;
  if (lane == 0) rowptr[0] = 0;
  for (int base = 0; base < N_NODES; base += 256) {
    const int i0 = base + (lane << 2);
    int4 c = {0, 0, 0, 0};
    if (i0 + 3 < N_NODES) c = *reinterpret_cast<const int4*>(cnt + i0);
    else {
      if (i0 + 0 < N_NODES) c.x = cnt[i0 + 0];
      if (i0 + 1 < N_NODES) c.y = cnt[i0 + 1];
      if (i0 + 2 < N_NODES) c.z = cnt[i0 + 2];
    }
    const int s4 = c.x + c.y + c.z + c.w;
    int v = s4;
#pragma unroll
    for (int off = 1; off < 64; off <<= 1) {
      const int t = __shfl_up(v, off);
      if (lane >= off) v += t;
    }
    const int ex = carry + v - s4;
    const int p1 = ex + c.x, p2 = p1 + c.y, p3 = p2 + c.z, p4 = p3 + c.w;
    if (i0 + 0 < N_NODES) rowptr[i0 + 1] = p1;
    if (i0 + 1 < N_NODES) rowptr[i0 + 2] = p2;
    if (i0 + 2 < N_NODES) rowptr[i0 + 3] = p3;
    if (i0 + 3 < N_NODES) rowptr[i0 + 4] = p4;
    carry += __shfl(v, 63);
  }
}

__global__ __launch_bounds__(256)
void fill_edges(const int* __restrict__ dst, const int* __restrict__ rowptr,
                int* __restrict__ cursor, int* __restrict__ eidx)
{
  const int e = blockIdx.x * 256 + threadIdx.x;
  if (e < N_EDGES) {
    const int d = dst[e];
    const int p = atomicAdd(&cursor[d], 1);
    eidx[rowptr[d] + p] = e;
  }
}

// ---------------- per-dst softmax + aggregation (one wave per node) ---------
// ODT: 0 -> bf16 out (intermediate), DT -> final out dtype
template<int DT, int ODT>
__global__ __launch_bounds__(256)
void gat_aggregate(const int* __restrict__ flag, int want,
                   const float* __restrict__ s, const int* __restrict__ rowptr,
                   const int* __restrict__ eidx, const int* __restrict__ src,
                   const u16* __restrict__ feat, const void* __restrict__ bias,
                   void* __restrict__ out)
{
  if (*flag != want) return;
  const int lane = threadIdx.x & 63;
  const int node = blockIdx.x * 4 + (threadIdx.x >> 6);
  if (node >= N_NODES) return;
  const int beg = rowptr[node], end = rowptr[node + 1];
  const int deg = end - beg;
  float acc[4] = {0.f, 0.f, 0.f, 0.f};
  if (deg > 0) {
    const int h = lane & 3, j = lane >> 2;
    float mloc = -__builtin_inff();
    for (int i = j; i < deg; i += 16) {
      const int e = eidx[beg + i];
      mloc = fmaxf(mloc, s[(size_t)e * 4 + h]);
    }
#pragma unroll
    for (int off = 4; off < 64; off <<= 1) mloc = fmaxf(mloc, __shfl_xor(mloc, off));
    float dloc = 0.f;
    for (int i = j; i < deg; i += 16) {
      const int e = eidx[beg + i];
      dloc += __expf(s[(size_t)e * 4 + h] - mloc);
    }
#pragma unroll
    for (int off = 4; off < 64; off <<= 1) dloc += __shfl_xor(dloc, off);
    float m_all[4], id_all[4];
#pragma unroll
    for (int hh = 0; hh < 4; ++hh) {
      m_all[hh]  = __shfl(mloc, hh);
      id_all[hh] = 1.f / fmaxf(__shfl(dloc, hh), 1e-9f);
    }
    for (int i = 0; i < deg; ++i) {
      const int e  = eidx[beg + i];
      const int sn = src[e];
      const float4 sv = *reinterpret_cast<const float4*>(s + (size_t)e * 4);
      const u16* frow = feat + (size_t)sn * 256;
      const float a0 = __expf(sv.x - m_all[0]) * id_all[0];
      const float a1 = __expf(sv.y - m_all[1]) * id_all[1];
      const float a2 = __expf(sv.z - m_all[2]) * id_all[2];
      const float a3 = __expf(sv.w - m_all[3]) * id_all[3];
      acc[0] = fmaf(a0, bf2f(frow[lane]),       acc[0]);
      acc[1] = fmaf(a1, bf2f(frow[64 + lane]),  acc[1]);
      acc[2] = fmaf(a2, bf2f(frow[128 + lane]), acc[2]);
      acc[3] = fmaf(a3, bf2f(frow[192 + lane]), acc[3]);
    }
  }
#pragma unroll
  for (int hh = 0; hh < 4; ++hh) {
    const int c = hh * 64 + lane;
    const float v = fmaxf(acc[hh] + ldf<DT>(bias, c), 0.f);
    if (ODT == 0) ((u16*)out)[(size_t)node * 256 + c] = f2bf(v);
    else          ((float*)out)[(size_t)node * 256 + c] = v;
  }
}

// ---------------- per-dtype pipeline ----------------------------------------
template<int DT>
static void run_pipeline(const int* flag, const void* features, const int* labels,
                         const int* src, const int* dst, const void* emb,
                         const void* le_W1, const void* le_b1, const void* ln_g,
                         const void* ln_b, const void* le_W2, const void* le_b2,
                         const void* W1, const void* al1, const void* ar1, const void* b1,
                         const void* W2, const void* al2, const void* ar2, const void* b2,
                         u16* y, u16* h, u16* feat, float* el, float* er, float* s,
                         u16* h2, const int* rowptr, const int* eidx,
                         void* outp, hipStream_t stream)
{
  gemm_bt<1, DT, DT><<<dim3(782, 16), 256, 0, stream>>>(flag, DT, nullptr, le_W1, le_b1, y,
                                                        features, emb, labels, N_NODES, 1024, 512);
  ln_relu<DT><<<N_NODES, 256, 0, stream>>>(flag, DT, y, ln_g, ln_b);
  gemm_bt<0, 0, DT><<<dim3(782, 4), 256, 0, stream>>>(flag, DT, y, le_W2, le_b2, h,
                                                      nullptr, nullptr, nullptr, N_NODES, 256, 1024);
  // GAT layer 1
  gemm_bt<0, 0, DT><<<dim3(782, 4), 256, 0, stream>>>(flag, DT, h, W1, nullptr, feat,
                                                      nullptr, nullptr, nullptr, N_NODES, 256, 256);
  gat_elr<DT><<<782, 256, 0, stream>>>(flag, DT, feat, al1, ar1, el, er);
  edge_scores<<<N_EDGES / 256, 256, 0, stream>>>(el, er, src, dst, s);
  gat_aggregate<DT, 0><<<12500, 256, 0, stream>>>(flag, DT, s, rowptr, eidx, src, feat, b1, h2);
  // GAT layer 2
  gemm_bt<0, 0, DT><<<dim3(782, 4), 256, 0, stream>>>(flag, DT, h2, W2, nullptr, feat,
                                                      nullptr, nullptr, nullptr, N_NODES, 256, 256);
  gat_elr<DT><<<782, 256, 0, stream>>>(flag, DT, feat, al2, ar2, el, er);
  edge_scores<<<N_EDGES / 256, 256, 0, stream>>>(el, er, src, dst, s);
  gat_aggregate<DT, DT><<<12500, 256, 0, stream>>>(flag, DT, s, rowptr, eidx, src, feat, b2, outp);
}

// ---------------- launch -----------------------------------------------------
// ws layout (bytes), peak ~131.6 MB (round-1 ran cleanly with writes at
// ws+131.6MB, so ws_size covers this):
//   [0, 102.4M)   y [N,1024] bf16; after G2 reused as:
//                 feat[0,25.6M) | el[25.6,26.4M) | er[26.4,27.2M) | s[27.2,40M) | h2[40,65.6M)
//   [102.4M,128M) h [N,256] bf16
//   [128M, ...]   rowptr | cnt/cursor | eidx | flag
extern "C" void kernel_launch(void* const* d_in, const int* in_sizes, int n_in,
                              void* d_out, int out_size, void* d_ws, size_t ws_size,
                              hipStream_t stream)
{
  const void* features = d_in[0];
  const int* labels    = (const int*)d_in[1];
  const int* src       = (const int*)d_in[2];
  const int* dst       = (const int*)d_in[3];
  const void* emb   = d_in[4];
  const void* le_W1 = d_in[5];
  const void* le_b1 = d_in[6];
  const void* ln_g  = d_in[7];
  const void* ln_b  = d_in[8];
  const void* le_W2 = d_in[9];
  const void* le_b2 = d_in[10];
  const void* W1    = d_in[11];
  const void* al1   = d_in[12];
  const void* ar1   = d_in[13];
  const void* b1    = d_in[14];
  const void* W2    = d_in[15];
  const void* al2   = d_in[16];
  const void* ar2   = d_in[17];
  const void* b2    = d_in[18];

  char* ws = (char*)d_ws;
  u16*   y      = (u16*)(ws + 0);
  u16*   h      = (u16*)(ws + 102400000);
  int*   rowptr = (int*)(ws + 128000000);
  int*   cnt    = (int*)(ws + 128000000 + 200064);
  int*   eidx   = (int*)(ws + 128000000 + 400128);
  int*   flag   = (int*)(ws + 128000000 + 3600128);
  u16*   feat   = (u16*)(ws + 0);
  float* el     = (float*)(ws + 25600000);
  float* er     = (float*)(ws + 26400000);
  float* s      = (float*)(ws + 27200000);
  u16*   h2     = (u16*)(ws + 40000000);

  detect_dtype<<<1, 64, 0, stream>>>((const u16*)features, flag);

  // CSR build (dtype-independent), reused by both GAT layers
  hipMemsetAsync(cnt, 0, N_NODES * 4, stream);
  count_edges<<<N_EDGES / 256, 256, 0, stream>>>(dst, cnt);
  scan_rowptr<<<1, 64, 0, stream>>>(cnt, rowptr);
  hipMemsetAsync(cnt, 0, N_NODES * 4, stream);
  fill_edges<<<N_EDGES / 256, 256, 0, stream>>>(dst, rowptr, cnt, eidx);

  run_pipeline<0>(flag, features, labels, src, dst, emb, le_W1, le_b1, ln_g, ln_b,
                  le_W2, le_b2, W1, al1, ar1, b1, W2, al2, ar2, b2,
                  y, h, feat, el, er, s, h2, rowptr, eidx, d_out, stream);
  run_pipeline<1>(flag, features, labels, src, dst, emb, le_W1, le_b1, ln_g, ln_b,
                  le_W2, le_b2, W1, al1, ar1, b1, W2, al2, ar2, b2,
                  y, h, feat, el, er, s, h2, rowptr, eidx, d_out, stream);
}

// Round 4
// 941.987 us; speedup vs baseline: 2.1228x; 2.1228x over previous
//
#include <hip/hip_runtime.h>
#include <hip/hip_bf16.h>

typedef unsigned short u16;
typedef unsigned int   u32;

#define N_NODES 50000
#define N_EDGES 800000

using s16x8 = __attribute__((ext_vector_type(8))) short;
using f32x4 = __attribute__((ext_vector_type(4))) float;

// bf16 helpers (RNE rounding)
__device__ __forceinline__ float bf2f(u16 u) {
  u32 x = ((u32)u) << 16;
  return __uint_as_float(x);
}
__device__ __forceinline__ u16 f2bf(float f) {
  u32 x = __float_as_uint(f);
  u32 r = (x + 0x7fffu + ((x >> 16) & 1u)) >> 16;
  return (u16)r;
}
__device__ __forceinline__ s16x8 cvt8_f32(const float* p) {
  const float4 f0 = *reinterpret_cast<const float4*>(p);
  const float4 f1 = *reinterpret_cast<const float4*>(p + 4);
  s16x8 v;
  v[0] = (short)f2bf(f0.x); v[1] = (short)f2bf(f0.y);
  v[2] = (short)f2bf(f0.z); v[3] = (short)f2bf(f0.w);
  v[4] = (short)f2bf(f1.x); v[5] = (short)f2bf(f1.y);
  v[6] = (short)f2bf(f1.z); v[7] = (short)f2bf(f1.w);
  return v;
}

// ---------------- dtype detector (unchanged from the passing round) ---------
__global__ __launch_bounds__(64)
void detect_dtype(const u16* __restrict__ feats, int* __restrict__ flag)
{
  const int lane = threadIdx.x;
  const u16 u = feats[lane * 2];
  const int ex = (u >> 7) & 0xFF;
  const unsigned long long m = __ballot(ex >= 137);
  if (lane == 0) *flag = (__popcll(m) > 8) ? 1 : 0;
}

// ---------------- normalize all weights/vectors to one bf16 arena -----------
// segments (u16 offsets): leW1 0 | leW2 524288 | W1 786432 | W2 851968 |
// leb1 917504 | lng 918528 | lnb 919552 | leb2 920576 | al1 920832 |
// ar1 921088 | b1 921344 | al2 921600 | ar2 921856 | b2 922112 | end 922368
template<int DT>
__global__ __launch_bounds__(256)
void conv_weights(const int* __restrict__ flag, int want,
                  const void* p0, const void* p1, const void* p2, const void* p3,
                  const void* p4, const void* p5, const void* p6, const void* p7,
                  const void* p8, const void* p9, const void* p10, const void* p11,
                  const void* p12, const void* p13, u16* __restrict__ arena)
{
  if (*flag != want) return;
  const int gi = blockIdx.x * 256 + threadIdx.x;
  if (gi >= 115296) return;
  const u32 g = (u32)gi * 8;
  const void* src; u32 rel;
  if      (g < 524288) { src = p0;  rel = g; }
  else if (g < 786432) { src = p1;  rel = g - 524288; }
  else if (g < 851968) { src = p2;  rel = g - 786432; }
  else if (g < 917504) { src = p3;  rel = g - 851968; }
  else if (g < 918528) { src = p4;  rel = g - 917504; }
  else if (g < 919552) { src = p5;  rel = g - 918528; }
  else if (g < 920576) { src = p6;  rel = g - 919552; }
  else if (g < 920832) { src = p7;  rel = g - 920576; }
  else if (g < 921088) { src = p8;  rel = g - 920832; }
  else if (g < 921344) { src = p9;  rel = g - 921088; }
  else if (g < 921600) { src = p10; rel = g - 921344; }
  else if (g < 921856) { src = p11; rel = g - 921600; }
  else if (g < 922112) { src = p12; rel = g - 921856; }
  else                 { src = p13; rel = g - 922112; }
  s16x8 v;
  if (DT == 0) v = *reinterpret_cast<const s16x8*>((const u16*)src + rel);
  else         v = cvt8_f32((const float*)src + rel);
  *reinterpret_cast<s16x8*>(arena + g) = v;
}

// ---------------- lab[n] = bf16(emb[labels[n]]) -----------------------------
template<int DT>
__global__ __launch_bounds__(256)
void build_lab(const int* __restrict__ flag, int want,
               const int* __restrict__ labels, const void* __restrict__ emb,
               u16* __restrict__ lab)
{
  if (*flag != want) return;
  const int gi = blockIdx.x * 256 + threadIdx.x;
  if (gi >= N_NODES * 32) return;
  const int row = gi >> 5, c8 = (gi & 31) * 8;
  const int e = labels[row];
  s16x8 v;
  if (DT == 0) v = *reinterpret_cast<const s16x8*>((const u16*)emb + (size_t)e * 256 + c8);
  else         v = cvt8_f32((const float*)emb + (size_t)e * 256 + c8);
  *reinterpret_cast<s16x8*>(lab + (size_t)row * 256 + c8) = v;
}

// ---------------- MFMA GEMM: C = A * B^T (+bias), bf16 in/out, f32 acc ------
// 128x128 tile, BK=64, 4 waves (2x2), per wave 4x4 frags of 16x16x32.
// LDS chunk-XOR swizzle (chunk ^= row&7), applied on write AND read.
// AMODE: 0 = plain A [M,K] bf16; 1 = concat(featsB bf16, lab) K=512;
//        2 = concat(featsF f32 -> bf16, lab) K=512.
template<int AMODE>
__global__ __launch_bounds__(256)
void gemm_mfma(const int* __restrict__ flag, int want,
               const u16* __restrict__ A, const u16* __restrict__ Bw,
               const u16* __restrict__ bias, u16* __restrict__ C,
               const u16* __restrict__ featsB, const float* __restrict__ featsF,
               const u16* __restrict__ lab, int M, int N, int K)
{
  if (want >= 0 && *flag != want) return;
  __shared__ u16 As[128 * 64];
  __shared__ u16 Bs[128 * 64];
  const int tid = threadIdx.x;
  const int w = tid >> 6, lane = tid & 63;
  const int wm = w >> 1, wn = w & 1;
  const int bm = blockIdx.x * 128, bn = blockIdx.y * 128;
  const int srow = lane >> 3;      // row within 8-row staging group
  const int q    = lane & 7;       // LDS 16B-chunk within 128B row

  f32x4 acc[4][4] = {};

  auto loadA = [&](int k0x, int jj) -> s16x8 {
    const int t  = w * 32 + jj * 8 + srow;
    const int cg = q ^ (t & 7);
    const int kg = k0x + cg * 8;
    const int r  = (bm + t < M) ? bm + t : M - 1;
    if (AMODE == 0)
      return *reinterpret_cast<const s16x8*>(A + (size_t)r * K + kg);
    if (AMODE == 1)
      return (kg < 256)
        ? *reinterpret_cast<const s16x8*>(featsB + (size_t)r * 256 + kg)
        : *reinterpret_cast<const s16x8*>(lab + (size_t)r * 256 + (kg - 256));
    // AMODE == 2
    if (kg < 256) return cvt8_f32(featsF + (size_t)r * 256 + kg);
    return *reinterpret_cast<const s16x8*>(lab + (size_t)r * 256 + (kg - 256));
  };
  auto loadB = [&](int k0x, int jj) -> s16x8 {
    const int t  = w * 32 + jj * 8 + srow;
    const int cg = q ^ (t & 7);
    return *reinterpret_cast<const s16x8*>(Bw + (size_t)(bn + t) * K + k0x + cg * 8);
  };

  for (int k0 = 0; k0 < K; k0 += 64) {
    s16x8 ra[4], rb[4];
#pragma unroll
    for (int jj = 0; jj < 4; ++jj) { ra[jj] = loadA(k0, jj); rb[jj] = loadB(k0, jj); }
#pragma unroll
    for (int jj = 0; jj < 4; ++jj) {
      const int t = w * 32 + jj * 8 + srow;
      *reinterpret_cast<s16x8*>(&As[t * 64 + q * 8]) = ra[jj];
      *reinterpret_cast<s16x8*>(&Bs[t * 64 + q * 8]) = rb[jj];
    }
    __syncthreads();
#pragma unroll
    for (int kk = 0; kk < 2; ++kk) {
      s16x8 af[4], bf[4];
#pragma unroll
      for (int i = 0; i < 4; ++i) {
        const int t = wm * 64 + i * 16 + (lane & 15);
        const int c = (kk * 4 + (lane >> 4)) ^ (t & 7);
        af[i] = *reinterpret_cast<const s16x8*>(&As[t * 64 + c * 8]);
      }
#pragma unroll
      for (int j = 0; j < 4; ++j) {
        const int t = wn * 64 + j * 16 + (lane & 15);
        const int c = (kk * 4 + (lane >> 4)) ^ (t & 7);
        bf[j] = *reinterpret_cast<const s16x8*>(&Bs[t * 64 + c * 8]);
      }
#pragma unroll
      for (int i = 0; i < 4; ++i)
#pragma unroll
        for (int j = 0; j < 4; ++j)
          acc[i][j] = __builtin_amdgcn_mfma_f32_16x16x32_bf16(af[i], bf[j], acc[i][j], 0, 0, 0);
    }
    __syncthreads();
  }
  // epilogue: C/D layout col=lane&15, row=(lane>>4)*4+reg  [m89-verified]
#pragma unroll
  for (int j = 0; j < 4; ++j) {
    const int col = bn + wn * 64 + j * 16 + (lane & 15);
    const float bv = bias ? bf2f(bias[col]) : 0.f;
#pragma unroll
    for (int i = 0; i < 4; ++i) {
      const int rbase = bm + wm * 64 + i * 16 + ((lane >> 4) << 2);
#pragma unroll
      for (int r = 0; r < 4; ++r) {
        const int row = rbase + r;
        if (row < M) C[(size_t)row * N + col] = f2bf(acc[i][j][r] + bv);
      }
    }
  }
}

// ---------------- LayerNorm(1024) + ReLU, in place, bf16 --------------------
__global__ __launch_bounds__(256)
void ln_relu(u16* __restrict__ y, const u16* __restrict__ g, const u16* __restrict__ b)
{
  const int row = blockIdx.x;
  u16* p = y + (size_t)row * 1024;
  const int t = threadIdx.x;
  const uint2 r = *reinterpret_cast<const uint2*>(p + (t << 2));
  float v[4] = { bf2f((u16)(r.x & 0xffffu)), bf2f((u16)(r.x >> 16)),
                 bf2f((u16)(r.y & 0xffffu)), bf2f((u16)(r.y >> 16)) };
  float s = v[0] + v[1] + v[2] + v[3];
  float qq = v[0]*v[0] + v[1]*v[1] + v[2]*v[2] + v[3]*v[3];
#pragma unroll
  for (int off = 1; off < 64; off <<= 1) { s += __shfl_xor(s, off); qq += __shfl_xor(qq, off); }
  __shared__ float ss[4], sq[4];
  const int w = t >> 6, lane = t & 63;
  if (lane == 0) { ss[w] = s; sq[w] = qq; }
  __syncthreads();
  const float tot  = ss[0] + ss[1] + ss[2] + ss[3];
  const float totq = sq[0] + sq[1] + sq[2] + sq[3];
  const float mu = tot * (1.f / 1024.f);
  const float var = totq * (1.f / 1024.f) - mu * mu;
  const float is = rsqrtf(var + 1e-5f);
  u16 o[4];
#pragma unroll
  for (int i = 0; i < 4; ++i) {
    const int c = (t << 2) + i;
    float val = (v[i] - mu) * is * bf2f(g[c]) + bf2f(b[c]);
    o[i] = f2bf(fmaxf(val, 0.f));
  }
  uint2 wv;
  wv.x = (u32)o[0] | ((u32)o[1] << 16);
  wv.y = (u32)o[2] | ((u32)o[3] << 16);
  *reinterpret_cast<uint2*>(p + (t << 2)) = wv;
}

// ---------------- el/er: one thread per (node, head) ------------------------
__global__ __launch_bounds__(256)
void gat_elr(const u16* __restrict__ feat, const u16* __restrict__ al,
             const u16* __restrict__ ar, float* __restrict__ el, float* __restrict__ er)
{
  const int idx = blockIdx.x * 256 + threadIdx.x;
  if (idx >= N_NODES * 4) return;
  const int n = idx >> 2, h = idx & 3;
  const u16* f  = feat + (size_t)n * 256 + h * 64;
  const u16* pl = al + h * 64;
  const u16* pr = ar + h * 64;
  float sl = 0.f, sr = 0.f;
#pragma unroll 8
  for (int d = 0; d < 64; ++d) {
    const float fv = bf2f(f[d]);
    sl = fmaf(fv, bf2f(pl[d]), sl);
    sr = fmaf(fv, bf2f(pr[d]), sr);
  }
  el[idx] = sl; er[idx] = sr;
}

// ---------------- edge scores: leaky_relu(el[src]+er[dst]) ------------------
__global__ __launch_bounds__(256)
void edge_scores(const float* __restrict__ el, const float* __restrict__ er,
                 const int* __restrict__ src, const int* __restrict__ dst,
                 float* __restrict__ s)
{
  const int e = blockIdx.x * 256 + threadIdx.x;
  if (e >= N_EDGES) return;
  const float4 l = *reinterpret_cast<const float4*>(el + (size_t)src[e] * 4);
  const float4 r = *reinterpret_cast<const float4*>(er + (size_t)dst[e] * 4);
  float4 o; float x;
  x = l.x + r.x; o.x = x > 0.f ? x : 0.2f * x;
  x = l.y + r.y; o.y = x > 0.f ? x : 0.2f * x;
  x = l.z + r.z; o.z = x > 0.f ? x : 0.2f * x;
  x = l.w + r.w; o.w = x > 0.f ? x : 0.2f * x;
  *reinterpret_cast<float4*>(s + (size_t)e * 4) = o;
}

// ---------------- CSR build (unchanged from passing round) ------------------
__global__ __launch_bounds__(256)
void count_edges(const int* __restrict__ dst, int* __restrict__ cnt)
{
  const int e = blockIdx.x * 256 + threadIdx.x;
  if (e < N_EDGES) atomicAdd(&cnt[dst[e]], 1);
}

__global__ __launch_bounds__(64)
void scan_rowptr(const int* __restrict__ cnt, int* __restrict__ rowptr)
{
  const int lane = threadIdx.x;
  int carry = 0;
  if (lane == 0) rowptr[0] = 0;
  for (int base = 0; base < N_NODES; base += 256) {
    const int i0 = base + (lane << 2);
    int4 c = {0, 0, 0, 0};
    if (i0 + 3 < N_NODES) c = *reinterpret_cast<const int4*>(cnt + i0);
    else {
      if (i0 + 0 < N_NODES) c.x = cnt[i0 + 0];
      if (i0 + 1 < N_NODES) c.y = cnt[i0 + 1];
      if (i0 + 2 < N_NODES) c.z = cnt[i0 + 2];
    }
    const int s4 = c.x + c.y + c.z + c.w;
    int v = s4;
#pragma unroll
    for (int off = 1; off < 64; off <<= 1) {
      const int t = __shfl_up(v, off);
      if (lane >= off) v += t;
    }
    const int ex = carry + v - s4;
    const int p1 = ex + c.x, p2 = p1 + c.y, p3 = p2 + c.z, p4 = p3 + c.w;
    if (i0 + 0 < N_NODES) rowptr[i0 + 1] = p1;
    if (i0 + 1 < N_NODES) rowptr[i0 + 2] = p2;
    if (i0 + 2 < N_NODES) rowptr[i0 + 3] = p3;
    if (i0 + 3 < N_NODES) rowptr[i0 + 4] = p4;
    carry += __shfl(v, 63);
  }
}

__global__ __launch_bounds__(256)
void fill_edges(const int* __restrict__ dst, const int* __restrict__ rowptr,
                int* __restrict__ cursor, int* __restrict__ eidx)
{
  const int e = blockIdx.x * 256 + threadIdx.x;
  if (e < N_EDGES) {
    const int d = dst[e];
    const int p = atomicAdd(&cursor[d], 1);
    eidx[rowptr[d] + p] = e;
  }
}

// ---------------- per-dst softmax + aggregation (one wave per node) ---------
template<int ODT>
__global__ __launch_bounds__(256)
void gat_aggregate(const int* __restrict__ flag, int want,
                   const float* __restrict__ s, const int* __restrict__ rowptr,
                   const int* __restrict__ eidx, const int* __restrict__ src,
                   const u16* __restrict__ feat, const u16* __restrict__ bias,
                   void* __restrict__ out)
{
  if (want >= 0 && *flag != want) return;
  const int lane = threadIdx.x & 63;
  const int node = blockIdx.x * 4 + (threadIdx.x >> 6);
  if (node >= N_NODES) return;
  const int beg = rowptr[node], end = rowptr[node + 1];
  const int deg = end - beg;
  float acc[4] = {0.f, 0.f, 0.f, 0.f};
  if (deg > 0) {
    const int h = lane & 3, j = lane >> 2;
    float mloc = -__builtin_inff();
    for (int i = j; i < deg; i += 16) {
      const int e = eidx[beg + i];
      mloc = fmaxf(mloc, s[(size_t)e * 4 + h]);
    }
#pragma unroll
    for (int off = 4; off < 64; off <<= 1) mloc = fmaxf(mloc, __shfl_xor(mloc, off));
    float dloc = 0.f;
    for (int i = j; i < deg; i += 16) {
      const int e = eidx[beg + i];
      dloc += __expf(s[(size_t)e * 4 + h] - mloc);
    }
#pragma unroll
    for (int off = 4; off < 64; off <<= 1) dloc += __shfl_xor(dloc, off);
    float m_all[4], id_all[4];
#pragma unroll
    for (int hh = 0; hh < 4; ++hh) {
      m_all[hh]  = __shfl(mloc, hh);
      id_all[hh] = 1.f / fmaxf(__shfl(dloc, hh), 1e-9f);
    }
    for (int i = 0; i < deg; ++i) {
      const int e  = eidx[beg + i];
      const int sn = src[e];
      const float4 sv = *reinterpret_cast<const float4*>(s + (size_t)e * 4);
      const u16* frow = feat + (size_t)sn * 256;
      const float a0 = __expf(sv.x - m_all[0]) * id_all[0];
      const float a1 = __expf(sv.y - m_all[1]) * id_all[1];
      const float a2 = __expf(sv.z - m_all[2]) * id_all[2];
      const float a3 = __expf(sv.w - m_all[3]) * id_all[3];
      acc[0] = fmaf(a0, bf2f(frow[lane]),       acc[0]);
      acc[1] = fmaf(a1, bf2f(frow[64 + lane]),  acc[1]);
      acc[2] = fmaf(a2, bf2f(frow[128 + lane]), acc[2]);
      acc[3] = fmaf(a3, bf2f(frow[192 + lane]), acc[3]);
    }
  }
#pragma unroll
  for (int hh = 0; hh < 4; ++hh) {
    const int c = hh * 64 + lane;
    const float v = fmaxf(acc[hh] + bf2f(bias[c]), 0.f);
    if (ODT == 0) ((u16*)out)[(size_t)node * 256 + c] = f2bf(v);
    else          ((float*)out)[(size_t)node * 256 + c] = v;
  }
}

// ---------------- launch -----------------------------------------------------
// ws layout (bytes), peak ~129.85 MB (proven ws_size >= 131.6 MB in r1/r3):
//   phase MLP : y [0, 102.4M) ; lab [102.4M, 128M)
//   phase GAT : feat[0,25.6M) h2[25.6,51.2) el[51.2,52.0) er[52.0,52.8)
//               s[52.8,65.6) rowptr[65.6M+] cnt[...] eidx[66.0M..69.2M)
//               (all inside dead-y region; CSR built AFTER gemm2)
//               h [102.4M,128M)  (overwrites dead lab)
//   arena [128M, 129.845M) bf16 weights ; flag
extern "C" void kernel_launch(void* const* d_in, const int* in_sizes, int n_in,
                              void* d_out, int out_size, void* d_ws, size_t ws_size,
                              hipStream_t stream)
{
  const void* features = d_in[0];
  const int* labels    = (const int*)d_in[1];
  const int* src       = (const int*)d_in[2];
  const int* dst       = (const int*)d_in[3];
  const void* emb   = d_in[4];
  const void* le_W1 = d_in[5];
  const void* le_b1 = d_in[6];
  const void* ln_g  = d_in[7];
  const void* ln_b  = d_in[8];
  const void* le_W2 = d_in[9];
  const void* le_b2 = d_in[10];
  const void* W1    = d_in[11];
  const void* al1   = d_in[12];
  const void* ar1   = d_in[13];
  const void* b1    = d_in[14];
  const void* W2    = d_in[15];
  const void* al2   = d_in[16];
  const void* ar2   = d_in[17];
  const void* b2    = d_in[18];

  char* ws = (char*)d_ws;
  u16*   y      = (u16*)(ws + 0);
  u16*   feat   = (u16*)(ws + 0);
  u16*   h2     = (u16*)(ws + 25600000);
  float* el     = (float*)(ws + 51200000);
  float* er     = (float*)(ws + 52000000);
  float* s      = (float*)(ws + 52800000);
  int*   rowptr = (int*)(ws + 65600000);
  int*   cnt    = (int*)(ws + 65800064);
  int*   eidx   = (int*)(ws + 66000128);
  u16*   lab    = (u16*)(ws + 102400000);
  u16*   h      = (u16*)(ws + 102400000);
  u16*   arena  = (u16*)(ws + 128000000);
  int*   flag   = (int*)(ws + 129844736);

  // arena segment pointers (u16 offsets)
  u16* aleW1 = arena + 0;
  u16* aleW2 = arena + 524288;
  u16* aW1   = arena + 786432;
  u16* aW2   = arena + 851968;
  u16* aleb1 = arena + 917504;
  u16* alng  = arena + 918528;
  u16* alnb  = arena + 919552;
  u16* aleb2 = arena + 920576;
  u16* aal1  = arena + 920832;
  u16* aar1  = arena + 921088;
  u16* ab1   = arena + 921344;
  u16* aal2  = arena + 921600;
  u16* aar2  = arena + 921856;
  u16* ab2   = arena + 922112;

  detect_dtype<<<1, 64, 0, stream>>>((const u16*)features, flag);

  conv_weights<0><<<451, 256, 0, stream>>>(flag, 0, le_W1, le_W2, W1, W2, le_b1, ln_g,
                                           ln_b, le_b2, al1, ar1, b1, al2, ar2, b2, arena);
  conv_weights<1><<<451, 256, 0, stream>>>(flag, 1, le_W1, le_W2, W1, W2, le_b1, ln_g,
                                           ln_b, le_b2, al1, ar1, b1, al2, ar2, b2, arena);
  build_lab<0><<<6250, 256, 0, stream>>>(flag, 0, labels, emb, lab);
  build_lab<1><<<6250, 256, 0, stream>>>(flag, 1, labels, emb, lab);

  // MLP: gemm1 (concat -> y), LN+ReLU, gemm2 (y -> h)
  gemm_mfma<1><<<dim3(391, 8), 256, 0, stream>>>(flag, 0, nullptr, aleW1, aleb1, y,
                                                 (const u16*)features, nullptr, lab,
                                                 N_NODES, 1024, 512);
  gemm_mfma<2><<<dim3(391, 8), 256, 0, stream>>>(flag, 1, nullptr, aleW1, aleb1, y,
                                                 nullptr, (const float*)features, lab,
                                                 N_NODES, 1024, 512);
  ln_relu<<<N_NODES, 256, 0, stream>>>(y, alng, alnb);
  gemm_mfma<0><<<dim3(391, 2), 256, 0, stream>>>(flag, -1, y, aleW2, aleb2, h,
                                                 nullptr, nullptr, nullptr,
                                                 N_NODES, 256, 1024);

  // CSR (after gemm2: lives in dead-y region)
  hipMemsetAsync(cnt, 0, N_NODES * 4, stream);
  count_edges<<<N_EDGES / 256, 256, 0, stream>>>(dst, cnt);
  scan_rowptr<<<1, 64, 0, stream>>>(cnt, rowptr);
  hipMemsetAsync(cnt, 0, N_NODES * 4, stream);
  fill_edges<<<N_EDGES / 256, 256, 0, stream>>>(dst, rowptr, cnt, eidx);

  // GAT layer 1
  gemm_mfma<0><<<dim3(391, 2), 256, 0, stream>>>(flag, -1, h, aW1, nullptr, feat,
                                                 nullptr, nullptr, nullptr,
                                                 N_NODES, 256, 256);
  gat_elr<<<782, 256, 0, stream>>>(feat, aal1, aar1, el, er);
  edge_scores<<<N_EDGES / 256, 256, 0, stream>>>(el, er, src, dst, s);
  gat_aggregate<0><<<12500, 256, 0, stream>>>(flag, -1, s, rowptr, eidx, src, feat, ab1, h2);

  // GAT layer 2
  gemm_mfma<0><<<dim3(391, 2), 256, 0, stream>>>(flag, -1, h2, aW2, nullptr, feat,
                                                 nullptr, nullptr, nullptr,
                                                 N_NODES, 256, 256);
  gat_elr<<<782, 256, 0, stream>>>(feat, aal2, aar2, el, er);
  edge_scores<<<N_EDGES / 256, 256, 0, stream>>>(el, er, src, dst, s);
  gat_aggregate<0><<<12500, 256, 0, stream>>>(flag, 0, s, rowptr, eidx, src, feat, ab2, d_out);
  gat_aggregate<1><<<12500, 256, 0, stream>>>(flag, 1, s, rowptr, eidx, src, feat, ab2, d_out);
}